// Round 10
// baseline (164.542 us; speedup 1.0000x reference)
//
#include <hip/hip_runtime.h>

#define N_NODES 50000
#define N_EDGES 600000
#define HID     128
#define NG      500
#define MAXDEG  48    // ELL slots; Poisson(12) max over 50k nodes ~30; +10 sigma safe
#define NEB     147   // edge-bin blocks: 147*4096 >= 600000
#define NBUCK   782   // ceil(50000/64) buckets of 64 nodes (dst>>6)
#define BCAP    1024  // edges per bucket capacity (mean 767, sigma 28 -> +9 sigma)

typedef __attribute__((ext_vector_type(8))) short short8;   // 8 bf16 (4 VGPRs)
typedef __attribute__((ext_vector_type(4))) float f32x4;

static __device__ __forceinline__ ushort f2bf(float f) {    // RNE f32 -> bf16 bits
    uint u = __float_as_uint(f);
    return (ushort)((u + 0x7fffu + ((u >> 16) & 1u)) >> 16);
}
static __device__ __forceinline__ float bf2f(ushort h) {
    return __uint_as_float(((uint)h) << 16);
}

// ---------------- Phase 1: bin edges by dst>>6 into bucket chunks (r2-proven version) ----
// Packed record: (src<<16) | (dst&63).  One global atomicAdd per (block,bucket).
// +5 special blocks: w3lin/starts precompute, W2 MFMA-fragment split-bf16 precompute.

__global__ __launch_bounds__(256) void k_bin(const int* __restrict__ src,
                                             const int* __restrict__ dst,
                                             int* __restrict__ gcnt,
                                             uint* __restrict__ ebuf,
                                             const float* __restrict__ W2,
                                             const float* __restrict__ W3,
                                             const float* __restrict__ Wlin,
                                             const float* __restrict__ b3,
                                             const float* __restrict__ blin,
                                             const int* __restrict__ batch,
                                             float* __restrict__ w3buf,
                                             ushort* __restrict__ w2fh,
                                             ushort* __restrict__ w2fl,
                                             int* __restrict__ starts) {
    if (blockIdx.x >= NEB) {
        int t = threadIdx.x;
        if (blockIdx.x == NEB) {
            // w3lin = W3 @ Wlin (128x2) + bias consts
            int k = t >> 1, j = t & 1;
            float acc = 0.f;
            for (int m = 0; m < 128; m++) acc += W3[k * 128 + m] * Wlin[m * 2 + j];
            w3buf[k * 2 + j] = acc;
            if (t < 2) {
                float c = 0.f;
                for (int m = 0; m < 128; m++) c += b3[m] * Wlin[m * 2 + t];
                w3buf[256 + t] = c + blin[t];   // const added to every non-empty graph
                w3buf[258 + t] = blin[t];       // empty-graph fallback
            }
            // per-graph start offsets (batch is sorted & constant)
            for (int g = t; g <= NG; g += 256) {
                int lo = 0, hi = N_NODES;
                while (lo < hi) { int mid = (lo + hi) >> 1; if (batch[mid] < g) lo = mid + 1; else hi = mid; }
                starts[g] = lo;
            }
        } else {
            // W2 -> split-bf16 (hi/lo), pre-swizzled into 16x16x32 MFMA B-fragment order:
            // elem idx = ((ntile*4 + ktile)*64 + lane)*8 + i ;
            // B[k][col] with k = ktile*32 + (lane>>4)*8 + i, col = ntile*16 + (lane&15)
            int q = blockIdx.x - (NEB + 1);          // 0..3
            for (int idx = q * 4096 + t; idx < (q + 1) * 4096; idx += 256) {
                int nt = idx >> 11, kt = (idx >> 9) & 3, ln = (idx >> 3) & 63, i = idx & 7;
                int k = kt * 32 + (ln >> 4) * 8 + i;
                int col = nt * 16 + (ln & 15);
                float v = W2[k * 128 + col];
                ushort h = f2bf(v);
                w2fh[idx] = h;
                w2fl[idx] = f2bf(v - bf2f(h));
            }
        }
        return;
    }
    __shared__ int lcnt[NBUCK];
    __shared__ int gbase[NBUCK];
    int t = threadIdx.x;
    for (int i = t; i < NBUCK; i += 256) lcnt[i] = 0;
    __syncthreads();
    uint pk[16];    // packed (src<<16)|(dst&63)
    uint blp[16];   // (bucket<<12)|local_slot ; 0xFFFFFFFF = invalid
    const int4* s4 = (const int4*)src;
    const int4* d4 = (const int4*)dst;
    int b4 = blockIdx.x * 1024;                 // 1024 int4 = 4096 edges per block
    #pragma unroll
    for (int u = 0; u < 4; u++) {
        int i4 = b4 + u * 256 + t;
        if (i4 < N_EDGES / 4) {
            int4 dv = d4[i4], sv = s4[i4];
            int dd[4] = {dv.x, dv.y, dv.z, dv.w};
            int ss[4] = {sv.x, sv.y, sv.z, sv.w};
            #pragma unroll
            for (int j = 0; j < 4; j++) {
                int b = dd[j] >> 6;
                int p = atomicAdd(&lcnt[b], 1);
                pk[u * 4 + j]  = ((uint)ss[j] << 16) | (uint)(dd[j] & 63);
                blp[u * 4 + j] = ((uint)b << 12) | (uint)p;
            }
        } else {
            #pragma unroll
            for (int j = 0; j < 4; j++) blp[u * 4 + j] = 0xFFFFFFFFu;
        }
    }
    __syncthreads();
    for (int i = t; i < NBUCK; i += 256) {
        int c = lcnt[i];
        gbase[i] = c ? atomicAdd(&gcnt[i], c) : 0;
    }
    __syncthreads();
    #pragma unroll
    for (int u = 0; u < 16; u++) {
        if (blp[u] != 0xFFFFFFFFu) {
            int b = (int)(blp[u] >> 12);
            int slot = gbase[b] + (int)(blp[u] & 0xFFFu);
            if (slot < BCAP) ebuf[b * BCAP + slot] = pk[u];
        }
    }
}

// ---------------- Phase 2: bucket -> node-major ELL + cnt + dinv + xd (nodeprep fused).
// One block per 64-node bucket (782 blocks = full chip); LDS-atomic slot assignment.

__global__ __launch_bounds__(256) void k_place(const int* __restrict__ gcnt,
                                               const uint* __restrict__ ebuf,
                                               const float* __restrict__ x,
                                               int* __restrict__ ell,
                                               int* __restrict__ cnt,
                                               float* __restrict__ dinv,
                                               float* __restrict__ xd) {
    int b = blockIdx.x;
    __shared__ int lc[64];
    int t = threadIdx.x;
    if (t < 64) lc[t] = 0;
    __syncthreads();
    int n = min(gcnt[b], BCAP);
    int d0 = b << 6;
    for (int i = t; i < n; i += 256) {
        uint e = ebuf[b * BCAP + i];
        int dl = (int)(e & 63u);
        int p = atomicAdd(&lc[dl], 1);
        if (p < MAXDEG) ell[(d0 + dl) * MAXDEG + p] = (int)(e >> 16);
    }
    __syncthreads();
    if (t < 64) {
        int d = d0 + t;
        if (d < N_NODES) {
            int c = lc[t];
            cnt[d] = c;                          // true in-degree
            float di = rsqrtf((float)c + 1.0f);
            dinv[d] = di;
            xd[d] = x[d] * di;
        }
    }
}

// layer-1 scalar aggregate, 8 lanes/node, node-major reads (32B contiguous per node):
// s1d[i] = {(xd_i + Σ xd_j)*di, di}   (x_i*di^2 == xd_i*di)
__global__ void k_s1d(const float* __restrict__ xd, const float* __restrict__ dinv,
                      const int* __restrict__ cnt, const int* __restrict__ ell,
                      float2* __restrict__ s1d) {
    int tid = blockIdx.x * 256 + threadIdx.x;
    int i = tid >> 3, sub = tid & 7;
    if (i >= N_NODES) return;
    int c = min(cnt[i], MAXDEG);
    float acc = 0.f;
    for (int p = sub; p < c; p += 8) acc += xd[ell[i * MAXDEG + p]];
    acc += __shfl_xor(acc, 1);
    acc += __shfl_xor(acc, 2);
    acc += __shfl_xor(acc, 4);
    if (sub == 0) {
        float di = dinv[i];
        float2 r = {(xd[i] + acc) * di, di};
        s1d[i] = r;
    }
}

// ---------------- Layer-2 input: H[i][128] = relu(s1_i W1+b1)di^2 + Σ_j relu(s1_j W1+b1)(dj di)
// v2 (r8 was neutral -> the aggregation ITSELF is the wall): 32 lanes/node =
// 2 edge-halves x 16 channel-groups x 8 ch.  ga[8]/w1r[8]/b1r[8] => ~45 VGPR ->
// __launch_bounds__(256,8) pins 8 waves/SIMD (genuinely fits, unlike r5's spill case).
// Per-lane edge chain c/2 (~6 iters) with 1-ahead software pipeline (next ell+s1d loads
// issue during current compute).  Divergence: max-c over 2 nodes/wave (~1.3x).
// Halves combine via __shfl_xor(.,16); h=0 lanes store 16B coalesced.

__global__ __launch_bounds__(256, 8) void k_h1(const float2* __restrict__ s1d,
                                               const int* __restrict__ cnt,
                                               const int* __restrict__ ell,
                                               const float* __restrict__ W1,
                                               const float* __restrict__ b1,
                                               ushort* __restrict__ hhi,
                                               ushort* __restrict__ hlo) {
    __shared__ float w1s[128], b1s[128];
    int t = threadIdx.x;
    if (t < 128) { w1s[t] = W1[t]; b1s[t] = b1[t]; }
    __syncthreads();
    int tid = blockIdx.x * 256 + t;
    int i = tid >> 5;                 // 32 lanes per node
    int sub = t & 31;
    int g = sub & 15;                 // channel group (8 channels)
    int h = sub >> 4;                 // edge half
    if (i >= N_NODES) return;
    float w1r[8], b1r[8];
    #pragma unroll
    for (int kk = 0; kk < 8; kk++) { w1r[kk] = w1s[g * 8 + kk]; b1r[kk] = b1s[g * 8 + kk]; }
    float2 sd = s1d[i];
    float di = sd.y;
    float ga[8];
    #pragma unroll
    for (int kk = 0; kk < 8; kk++)
        ga[kk] = h ? 0.f : fmaxf(sd.x * w1r[kk] + b1r[kk], 0.f) * (di * di);
    int c = min(cnt[i], MAXDEG);
    const int* row = &ell[i * MAXDEG];
    int p = h;
    if (p < c) {
        float2 s = s1d[row[p]];                 // prologue load
        for (p += 2;; p += 2) {
            bool more = (p < c);
            float2 sn;
            if (more) sn = s1d[row[p]];         // next-iter load overlaps compute below
            float wj = s.y * di;
            #pragma unroll
            for (int kk = 0; kk < 8; kk++)
                ga[kk] += fmaxf(s.x * w1r[kk] + b1r[kk], 0.f) * wj;
            if (!more) break;
            s = sn;
        }
    }
    // combine edge halves (lane ^ 16 stays inside the 32-lane node group)
    #pragma unroll
    for (int kk = 0; kk < 8; kk++) ga[kk] += __shfl_xor(ga[kk], 16);
    if (h == 0) {
        uint hv[4], lv[4];
        #pragma unroll
        for (int kk = 0; kk < 8; kk += 2) {
            ushort h0 = f2bf(ga[kk]);      ushort l0 = f2bf(ga[kk]     - bf2f(h0));
            ushort h1v = f2bf(ga[kk + 1]); ushort l1v = f2bf(ga[kk + 1] - bf2f(h1v));
            hv[kk >> 1] = (uint)h0 | ((uint)h1v << 16);
            lv[kk >> 1] = (uint)l0 | ((uint)l1v << 16);
        }
        *(uint4*)&hhi[i * 128 + g * 8] = make_uint4(hv[0], hv[1], hv[2], hv[3]);
        *(uint4*)&hlo[i * 128 + g * 8] = make_uint4(lv[0], lv[1], lv[2], lv[3]);
    }
}

// ---------------- Dense MFMA GEMM: zd = proj(relu(H @ W2 + b2)) * dinv.
// 64-row tile, 256 threads = 4 waves, each wave owns 2 ntiles (32 cols).  A-frags read
// DIRECTLY from global H (row-major == frag layout, 16B aligned); B-frags from L2-resident
// pre-swizzled w2f.  One barrier total; split-bf16 (3 MFMA) keeps fp32-level precision.
// mfma_f32_16x16x32_bf16: A row=lane&15, k=(lane>>4)*8+i ; B col=lane&15 ;
// D col=lane&15, row=(lane>>4)*4+reg  (m89-verified mapping)

__global__ __launch_bounds__(256, 4) void k_gemm2(const ushort* __restrict__ hhi,
                                                  const ushort* __restrict__ hlo,
                                                  const ushort* __restrict__ w2fh,
                                                  const ushort* __restrict__ w2fl,
                                                  const float* __restrict__ b2,
                                                  const float* __restrict__ w3buf,
                                                  const float* __restrict__ dinv,
                                                  float* __restrict__ zd) {
    __shared__ float zpart[4 * 64 * 2];   // 2 KB
    int t = threadIdx.x;
    int r0 = blockIdx.x * 64;
    int wv = t >> 6, l = t & 63, l15 = l & 15, lk = l >> 4;
    const short8* Bh = (const short8*)w2fh;
    const short8* Bl = (const short8*)w2fl;
    f32x4 acc[4][2];
    #pragma unroll
    for (int mt = 0; mt < 4; mt++)
        #pragma unroll
        for (int nt = 0; nt < 2; nt++) acc[mt][nt] = (f32x4){0.f, 0.f, 0.f, 0.f};
    #pragma unroll
    for (int kt = 0; kt < 4; kt++) {
        short8 bh0 = Bh[((2 * wv) * 4 + kt) * 64 + l];
        short8 bl0 = Bl[((2 * wv) * 4 + kt) * 64 + l];
        short8 bh1 = Bh[((2 * wv + 1) * 4 + kt) * 64 + l];
        short8 bl1 = Bl[((2 * wv + 1) * 4 + kt) * 64 + l];
        #pragma unroll
        for (int mt = 0; mt < 4; mt++) {
            int row = min(r0 + mt * 16 + l15, N_NODES - 1);   // clamp: junk rows masked at store
            int off = row * 128 + kt * 32 + lk * 8;
            short8 ah = *(const short8*)&hhi[off];
            short8 al = *(const short8*)&hlo[off];
            acc[mt][0] = __builtin_amdgcn_mfma_f32_16x16x32_bf16(ah, bh0, acc[mt][0], 0, 0, 0);
            acc[mt][0] = __builtin_amdgcn_mfma_f32_16x16x32_bf16(ah, bl0, acc[mt][0], 0, 0, 0);
            acc[mt][0] = __builtin_amdgcn_mfma_f32_16x16x32_bf16(al, bh0, acc[mt][0], 0, 0, 0);
            acc[mt][1] = __builtin_amdgcn_mfma_f32_16x16x32_bf16(ah, bh1, acc[mt][1], 0, 0, 0);
            acc[mt][1] = __builtin_amdgcn_mfma_f32_16x16x32_bf16(ah, bl1, acc[mt][1], 0, 0, 0);
            acc[mt][1] = __builtin_amdgcn_mfma_f32_16x16x32_bf16(al, bh1, acc[mt][1], 0, 0, 0);
        }
    }
    // epilogue: relu(+b2), project to 2 outputs (both ntiles), 16-lane reduce, stash
    int cg0 = (2 * wv) * 16 + l15, cg1 = (2 * wv + 1) * 16 + l15;
    float b20 = b2[cg0], w00 = w3buf[cg0 * 2], w10 = w3buf[cg0 * 2 + 1];
    float b21 = b2[cg1], w01 = w3buf[cg1 * 2], w11 = w3buf[cg1 * 2 + 1];
    #pragma unroll
    for (int mt = 0; mt < 4; mt++) {
        #pragma unroll
        for (int r = 0; r < 4; r++) {
            float v0 = fmaxf(acc[mt][0][r] + b20, 0.f);
            float v1 = fmaxf(acc[mt][1][r] + b21, 0.f);
            float q0 = v0 * w00 + v1 * w01;
            float q1 = v0 * w10 + v1 * w11;
            #pragma unroll
            for (int o = 1; o < 16; o <<= 1) {
                q0 += __shfl_xor(q0, o);
                q1 += __shfl_xor(q1, o);
            }
            if (l15 == 0) {
                int rl = mt * 16 + lk * 4 + r;
                zpart[(wv * 64 + rl) * 2 + 0] = q0;
                zpart[(wv * 64 + rl) * 2 + 1] = q1;
            }
        }
    }
    __syncthreads();
    if (t < 128) {
        int rl = t >> 1, o = t & 1;
        float s = zpart[rl * 2 + o] + zpart[(64 + rl) * 2 + o]
                + zpart[(128 + rl) * 2 + o] + zpart[(192 + rl) * 2 + o];
        int rg = r0 + rl;
        if (rg < N_NODES) zd[rg * 2 + o] = s * dinv[rg];
    }
}

// ---------------- Layer-3 aggregation + pool: 8 lanes/node, segmented scan, ~2 atomics/block
// into gsum.  NO device fence / ticket (r4-r6 lesson: per-block __threadfence + ticket
// atomic across 1563 blocks cost ~+39 us total).

__global__ void k_aggz(const float* __restrict__ zd, const int* __restrict__ cnt,
                       const int* __restrict__ ell, const float* __restrict__ dinv,
                       const int* __restrict__ batch, float* __restrict__ gsum) {
    __shared__ float sa0[32], sa1[32];
    __shared__ int sg[32];
    int tid = blockIdx.x * 256 + threadIdx.x;
    int t = threadIdx.x;
    int i = tid >> 3, sub = tid & 7;
    const float2* Z = (const float2*)zd;
    float a0 = 0.f, a1 = 0.f;
    if (i < N_NODES) {
        int c = min(cnt[i], MAXDEG);
        for (int p = sub; p < c; p += 8) {
            float2 zj = Z[ell[i * MAXDEG + p]];
            a0 += zj.x; a1 += zj.y;
        }
    }
    a0 += __shfl_xor(a0, 1); a1 += __shfl_xor(a1, 1);
    a0 += __shfl_xor(a0, 2); a1 += __shfl_xor(a1, 2);
    a0 += __shfl_xor(a0, 4); a1 += __shfl_xor(a1, 4);
    if (sub == 0) {
        int li = t >> 3;
        if (i < N_NODES) {
            float di = dinv[i];
            float2 zi = Z[i];
            sa0[li] = (zi.x + a0) * di;     // az_i = zd_i*di + di*Σ zd_j
            sa1[li] = (zi.y + a1) * di;
            sg[li] = batch[i];
        } else { sa0[li] = 0.f; sa1[li] = 0.f; sg[li] = -1; }
    }
    __syncthreads();
    if (t < 32) {
        float v0 = sa0[t], v1 = sa1[t];
        int g = sg[t];
        #pragma unroll
        for (int o = 1; o < 32; o <<= 1) {   // segmented inclusive scan (batch sorted)
            float u0 = __shfl_up(v0, o), u1 = __shfl_up(v1, o);
            int ug = __shfl_up(g, o);
            if (t >= o && ug == g) { v0 += u0; v1 += u1; }
        }
        int gn = __shfl_down(g, 1);
        bool last = (t == 31) || (g != gn);
        if (last && g >= 0) {
            atomicAdd(&gsum[g * 2 + 0], v0);
            atomicAdd(&gsum[g * 2 + 1], v1);
        }
    }
}

// ---------------- Final: 1 block — per-graph mean + consts ----------------

__global__ __launch_bounds__(256) void k_final2(const float* __restrict__ gsum,
                                                const int* __restrict__ starts,
                                                const float* __restrict__ w3buf,
                                                float* __restrict__ out) {
    int t = threadIdx.x;
    for (int g = t; g < NG; g += 256) {
        int c = starts[g + 1] - starts[g];
        if (c > 0) {
            float inv = 1.0f / (float)c;
            out[g * 2 + 0] = gsum[g * 2 + 0] * inv + w3buf[256];
            out[g * 2 + 1] = gsum[g * 2 + 1] * inv + w3buf[257];
        } else {
            out[g * 2 + 0] = w3buf[258];
            out[g * 2 + 1] = w3buf[259];
        }
    }
}

// ---------------- launch ----------------

extern "C" void kernel_launch(void* const* d_in, const int* in_sizes, int n_in,
                              void* d_out, int out_size, void* d_ws, size_t ws_size,
                              hipStream_t stream) {
    const float* x    = (const float*)d_in[0];
    const float* W1   = (const float*)d_in[1];
    const float* b1   = (const float*)d_in[2];
    const float* W2   = (const float*)d_in[3];
    const float* b2   = (const float*)d_in[4];
    const float* W3   = (const float*)d_in[5];
    const float* b3   = (const float*)d_in[6];
    const float* Wlin = (const float*)d_in[7];
    const float* blin = (const float*)d_in[8];
    const int*   eidx = (const int*)d_in[9];
    const int*   batch= (const int*)d_in[10];
    const int* esrc = eidx;
    const int* edst = eidx + N_EDGES;
    float* out = (float*)d_out;

    char* w = (char*)d_ws;
    size_t off = 0;
    auto alloc = [&](size_t bytes) { size_t o = off; off = (off + bytes + 255) & ~(size_t)255; return o; };
    int*   cnt    = (int*)  (w + alloc(N_NODES * 4));
    int*   ell    = (int*)  (w + alloc((size_t)N_NODES * MAXDEG * 4));   // 9.6 MB, node-major
    float* dinv   = (float*)(w + alloc(N_NODES * 4));
    float* xd     = (float*)(w + alloc(N_NODES * 4));
    float2* s1d   = (float2*)(w + alloc((size_t)N_NODES * 8));
    float* w3buf  = (float*)(w + alloc(260 * 4));
    float* zd     = (float*)(w + alloc((size_t)N_NODES * 2 * 4));
    ushort* w2fh  = (ushort*)(w + alloc(16384 * 2));   // W2 bf16-hi, MFMA B-frag order
    ushort* w2fl  = (ushort*)(w + alloc(16384 * 2));   // W2 bf16-lo
    ushort* hhi   = (ushort*)(w + alloc((size_t)N_NODES * 128 * 2));  // 12.8 MB H bf16-hi
    ushort* hlo   = (ushort*)(w + alloc((size_t)N_NODES * 128 * 2));  // 12.8 MB H bf16-lo
    int*   starts = (int*)  (w + alloc((NG + 4) * 4)); // per-graph node range starts
    int*   gcnt   = (int*)  (w + alloc(1024 * 4));     // bucket cursors [782]
    float* gsum   = (float*)(w + alloc(NG * 2 * 4));   // pooled sums (contiguous after gcnt)
    uint*  ebuf   = (uint*) (w + alloc((size_t)NBUCK * BCAP * 4));  // 3.2 MB bucket records

    const int QB  = (N_NODES * 8 + 255) / 256;    // 1563 (8 lanes/node)
    const int QB2 = (N_NODES * 32 + 255) / 256;   // 6250 (32 lanes/node)
    // 1: zero bucket cursors + graph accumulators (one contiguous memset)
    hipMemsetAsync(gcnt, 0, 1024 * 4 + NG * 2 * 4, stream);
    // 2: bin edges into bucket chunks + w3lin / starts / W2-frag precompute
    k_bin<<<NEB + 5, 256, 0, stream>>>(esrc, edst, gcnt, ebuf, W2, W3, Wlin, b3, blin,
                                       batch, w3buf, w2fh, w2fl, starts);
    // 3: buckets -> node-major ELL + cnt + dinv + xd (nodeprep fused)
    k_place<<<NBUCK, 256, 0, stream>>>(gcnt, ebuf, x, ell, cnt, dinv, xd);
    // 4: layer-1 scalar aggregate (8 lanes/node, node-major)
    k_s1d<<<QB, 256, 0, stream>>>(xd, dinv, cnt, ell, s1d);
    // 5: layer-2 input H (aggregation + relu reconstruct) -> global bf16 hi/lo (32 lanes/node)
    k_h1<<<QB2, 256, 0, stream>>>(s1d, cnt, ell, W1, b1, hhi, hlo);
    // 6: dense MFMA GEMM + relu + projection -> zd [N,2]
    k_gemm2<<<NBUCK, 256, 0, stream>>>(hhi, hlo, w2fh, w2fl, b2, w3buf, dinv, zd);
    // 7: layer-3 aggregation + pooled segment sums
    k_aggz<<<QB, 256, 0, stream>>>(zd, cnt, ell, dinv, batch, gsum);
    // 8: per-graph mean + consts (1 block)
    k_final2<<<1, 256, 0, stream>>>(gsum, starts, w3buf, out);
}

// Round 11
// 144.041 us; speedup vs baseline: 1.1423x; 1.1423x over previous
//
#include <hip/hip_runtime.h>

#define N_NODES 50000
#define N_EDGES 600000
#define HID     128
#define NG      500
#define MAXDEG  48    // ELL slots; Poisson(12) max over 50k nodes ~30; +10 sigma safe
#define ECAP    664   // compact LDS staging capacity (32 rows x mean 12 = 384; +14 sigma)
#define NEB     147   // edge-bin blocks: 147*4096 >= 600000
#define NBUCK   782   // ceil(50000/64) buckets of 64 nodes (dst>>6)
#define BCAP    1024  // edges per bucket capacity (mean 767, sigma 28 -> +9 sigma)

typedef __attribute__((ext_vector_type(8))) short short8;   // 8 bf16 (4 VGPRs)
typedef __attribute__((ext_vector_type(4))) float f32x4;

static __device__ __forceinline__ ushort f2bf(float f) {    // RNE f32 -> bf16 bits
    uint u = __float_as_uint(f);
    return (ushort)((u + 0x7fffu + ((u >> 16) & 1u)) >> 16);
}
static __device__ __forceinline__ float bf2f(ushort h) {
    return __uint_as_float(((uint)h) << 16);
}

// ---------------- Phase 1: bin edges by dst>>6 into bucket chunks (r2-proven version) ----
// Packed record: (src<<16) | (dst&63).  One global atomicAdd per (block,bucket).
// +5 special blocks: w3lin/starts precompute, W2 MFMA-fragment split-bf16 precompute.

__global__ __launch_bounds__(256) void k_bin(const int* __restrict__ src,
                                             const int* __restrict__ dst,
                                             int* __restrict__ gcnt,
                                             uint* __restrict__ ebuf,
                                             const float* __restrict__ W2,
                                             const float* __restrict__ W3,
                                             const float* __restrict__ Wlin,
                                             const float* __restrict__ b3,
                                             const float* __restrict__ blin,
                                             const int* __restrict__ batch,
                                             float* __restrict__ w3buf,
                                             ushort* __restrict__ w2fh,
                                             ushort* __restrict__ w2fl,
                                             int* __restrict__ starts) {
    if (blockIdx.x >= NEB) {
        int t = threadIdx.x;
        if (blockIdx.x == NEB) {
            // w3lin = W3 @ Wlin (128x2) + bias consts
            int k = t >> 1, j = t & 1;
            float acc = 0.f;
            for (int m = 0; m < 128; m++) acc += W3[k * 128 + m] * Wlin[m * 2 + j];
            w3buf[k * 2 + j] = acc;
            if (t < 2) {
                float c = 0.f;
                for (int m = 0; m < 128; m++) c += b3[m] * Wlin[m * 2 + t];
                w3buf[256 + t] = c + blin[t];   // const added to every non-empty graph
                w3buf[258 + t] = blin[t];       // empty-graph fallback
            }
            // per-graph start offsets (batch is sorted & constant)
            for (int g = t; g <= NG; g += 256) {
                int lo = 0, hi = N_NODES;
                while (lo < hi) { int mid = (lo + hi) >> 1; if (batch[mid] < g) lo = mid + 1; else hi = mid; }
                starts[g] = lo;
            }
        } else {
            // W2 -> split-bf16 (hi/lo), pre-swizzled into 16x16x32 MFMA B-fragment order:
            // elem idx = ((ntile*4 + ktile)*64 + lane)*8 + i ;
            // B[k][col] with k = ktile*32 + (lane>>4)*8 + i, col = ntile*16 + (lane&15)
            int q = blockIdx.x - (NEB + 1);          // 0..3
            for (int idx = q * 4096 + t; idx < (q + 1) * 4096; idx += 256) {
                int nt = idx >> 11, kt = (idx >> 9) & 3, ln = (idx >> 3) & 63, i = idx & 7;
                int k = kt * 32 + (ln >> 4) * 8 + i;
                int col = nt * 16 + (ln & 15);
                float v = W2[k * 128 + col];
                ushort h = f2bf(v);
                w2fh[idx] = h;
                w2fl[idx] = f2bf(v - bf2f(h));
            }
        }
        return;
    }
    __shared__ int lcnt[NBUCK];
    __shared__ int gbase[NBUCK];
    int t = threadIdx.x;
    for (int i = t; i < NBUCK; i += 256) lcnt[i] = 0;
    __syncthreads();
    uint pk[16];    // packed (src<<16)|(dst&63)
    uint blp[16];   // (bucket<<12)|local_slot ; 0xFFFFFFFF = invalid
    const int4* s4 = (const int4*)src;
    const int4* d4 = (const int4*)dst;
    int b4 = blockIdx.x * 1024;                 // 1024 int4 = 4096 edges per block
    #pragma unroll
    for (int u = 0; u < 4; u++) {
        int i4 = b4 + u * 256 + t;
        if (i4 < N_EDGES / 4) {
            int4 dv = d4[i4], sv = s4[i4];
            int dd[4] = {dv.x, dv.y, dv.z, dv.w};
            int ss[4] = {sv.x, sv.y, sv.z, sv.w};
            #pragma unroll
            for (int j = 0; j < 4; j++) {
                int b = dd[j] >> 6;
                int p = atomicAdd(&lcnt[b], 1);
                pk[u * 4 + j]  = ((uint)ss[j] << 16) | (uint)(dd[j] & 63);
                blp[u * 4 + j] = ((uint)b << 12) | (uint)p;
            }
        } else {
            #pragma unroll
            for (int j = 0; j < 4; j++) blp[u * 4 + j] = 0xFFFFFFFFu;
        }
    }
    __syncthreads();
    for (int i = t; i < NBUCK; i += 256) {
        int c = lcnt[i];
        gbase[i] = c ? atomicAdd(&gcnt[i], c) : 0;
    }
    __syncthreads();
    #pragma unroll
    for (int u = 0; u < 16; u++) {
        if (blp[u] != 0xFFFFFFFFu) {
            int b = (int)(blp[u] >> 12);
            int slot = gbase[b] + (int)(blp[u] & 0xFFFu);
            if (slot < BCAP) ebuf[b * BCAP + slot] = pk[u];
        }
    }
}

// ---------------- Phase 2: bucket -> node-major ELL + cnt + dinv + xd (nodeprep fused).
// One block per 64-node bucket (782 blocks = full chip); LDS-atomic slot assignment.

__global__ __launch_bounds__(256) void k_place(const int* __restrict__ gcnt,
                                               const uint* __restrict__ ebuf,
                                               const float* __restrict__ x,
                                               int* __restrict__ ell,
                                               int* __restrict__ cnt,
                                               float* __restrict__ dinv,
                                               float* __restrict__ xd) {
    int b = blockIdx.x;
    __shared__ int lc[64];
    int t = threadIdx.x;
    if (t < 64) lc[t] = 0;
    __syncthreads();
    int n = min(gcnt[b], BCAP);
    int d0 = b << 6;
    for (int i = t; i < n; i += 256) {
        uint e = ebuf[b * BCAP + i];
        int dl = (int)(e & 63u);
        int p = atomicAdd(&lc[dl], 1);
        if (p < MAXDEG) ell[(d0 + dl) * MAXDEG + p] = (int)(e >> 16);
    }
    __syncthreads();
    if (t < 64) {
        int d = d0 + t;
        if (d < N_NODES) {
            int c = lc[t];
            cnt[d] = c;                          // true in-degree
            float di = rsqrtf((float)c + 1.0f);
            dinv[d] = di;
            xd[d] = x[d] * di;
        }
    }
}

// layer-1 scalar aggregate, 8 lanes/node, node-major reads (32B contiguous per node):
// s1d[i] = {(xd_i + Σ xd_j)*di, di}   (x_i*di^2 == xd_i*di)
__global__ void k_s1d(const float* __restrict__ xd, const float* __restrict__ dinv,
                      const int* __restrict__ cnt, const int* __restrict__ ell,
                      float2* __restrict__ s1d) {
    int tid = blockIdx.x * 256 + threadIdx.x;
    int i = tid >> 3, sub = tid & 7;
    if (i >= N_NODES) return;
    int c = min(cnt[i], MAXDEG);
    float acc = 0.f;
    for (int p = sub; p < c; p += 8) acc += xd[ell[i * MAXDEG + p]];
    acc += __shfl_xor(acc, 1);
    acc += __shfl_xor(acc, 2);
    acc += __shfl_xor(acc, 4);
    if (sub == 0) {
        float di = dinv[i];
        float2 r = {(xd[i] + acc) * di, di};
        s1d[i] = r;
    }
}

// ---------------- Fused: reconstruct-aggregate g=A·h1, MFMA GEMM g@W2 (split-bf16),
// relu+b2, ·w3lin -> zd[N,2].  32-row tile; compact LDS staging; H tile stored as bf16
// hi/lo row-major (stride 136 -> 16B-aligned ds_read_b128 A-frags, 2-way banks = free).
// Split-bf16 product AhBh+AhBl+AlBh keeps fp32-level precision (~1e-5 rel) with MFMA rate.
// EXACT r4 best-measured version (145.6 us total): every later variant (64-row/512t,
// h1/gemm2 split, 32-lane gather) measured neutral; this is the clean re-baseline.

__global__ __launch_bounds__(256, 8) void k_gemm_fused(const float2* __restrict__ s1d,
                                                       const int* __restrict__ cnt,
                                                       const int* __restrict__ ell,
                                                       const float* __restrict__ W1,
                                                       const float* __restrict__ b1,
                                                       const ushort* __restrict__ w2fh,
                                                       const ushort* __restrict__ w2fl,
                                                       const float* __restrict__ b2,
                                                       const float* __restrict__ w3buf,
                                                       const float* __restrict__ dinv,
                                                       float* __restrict__ zd) {
    __shared__ __align__(16) ushort Hhi[32 * 136];   // 8704 B, [row][136] bf16-hi
    __shared__ __align__(16) ushort Hlo[32 * 136];   // 8704 B, bf16-lo
    __shared__ float2 sjd_sh[ECAP];                  // 5312 B, compacted; reused as zpart
    __shared__ int cnt_sh[32];
    __shared__ int pref_sh[33];                      // exclusive prefix; pref_sh[32] = total
    int t = threadIdx.x;
    int r0 = blockIdx.x * 32;
    int lane = t & 31, grp = t >> 5;  // lane = row in tile, grp = 16-channel chunk (8 x 16)

    if (t < 32) {
        int i = r0 + t;
        int c = (i < N_NODES) ? min(cnt[i], MAXDEG) : 0;
        cnt_sh[t] = c;
        int inc = c;
        for (int o = 1; o < 32; o <<= 1) {
            int u = __shfl_up(inc, o);
            if (t >= o) inc += u;
        }
        pref_sh[t] = inc - c;
        if (t == 31) pref_sh[32] = inc;
    }
    __syncthreads();
    int total = pref_sh[32];
    bool fast = (total <= ECAP);
    if (fast) {
        // staging: linear sweep of the tile's [32][48] node-major slots, fully coalesced
        #pragma unroll
        for (int u = 0; u < 6; u++) {            // 6*256 = 1536 = 32*MAXDEG
            int s = u * 256 + t;
            int ln = s / MAXDEG, p = s - ln * MAXDEG;
            if (p < cnt_sh[ln]) {
                int j = ell[(r0 + ln) * MAXDEG + p];
                sjd_sh[pref_sh[ln] + p] = s1d[j];
            }
        }
    }
    __syncthreads();

    float w1r[16], b1r[16];
    #pragma unroll
    for (int kk = 0; kk < 16; kk++) { w1r[kk] = W1[grp * 16 + kk]; b1r[kk] = b1[grp * 16 + kk]; }

    float ga[16];
    #pragma unroll
    for (int kk = 0; kk < 16; kk++) ga[kk] = 0.f;
    int node = r0 + lane;
    if (node < N_NODES) {
        float2 sd = s1d[node];
        float di = sd.y, wself = sd.y * sd.y;
        #pragma unroll
        for (int kk = 0; kk < 16; kk++) ga[kk] = fmaxf(sd.x * w1r[kk] + b1r[kk], 0.f) * wself;
        int c = cnt_sh[lane];
        if (fast) {
            const float2* myrow = &sjd_sh[pref_sh[lane]];
            int p = 0;
            for (; p + 3 < c; p += 4) {
                float2 s0 = myrow[p], s1v = myrow[p+1], s2 = myrow[p+2], s3 = myrow[p+3];
                float wj0 = s0.y * di, wj1 = s1v.y * di, wj2 = s2.y * di, wj3 = s3.y * di;
                #pragma unroll
                for (int kk = 0; kk < 16; kk++) {
                    ga[kk] += fmaxf(s0.x  * w1r[kk] + b1r[kk], 0.f) * wj0
                            + fmaxf(s1v.x * w1r[kk] + b1r[kk], 0.f) * wj1
                            + fmaxf(s2.x  * w1r[kk] + b1r[kk], 0.f) * wj2
                            + fmaxf(s3.x  * w1r[kk] + b1r[kk], 0.f) * wj3;
                }
            }
            for (; p < c; p++) {
                float2 sj = myrow[p];
                float wj = sj.y * di;
                #pragma unroll
                for (int kk = 0; kk < 16; kk++)
                    ga[kk] += fmaxf(sj.x * w1r[kk] + b1r[kk], 0.f) * wj;
            }
        } else {   // overflow fallback (block-uniform, ~never taken)
            for (int p = 0; p < c; p++) {
                float2 sj = s1d[ell[node * MAXDEG + p]];
                float wj = sj.y * di;
                #pragma unroll
                for (int kk = 0; kk < 16; kk++)
                    ga[kk] += fmaxf(sj.x * w1r[kk] + b1r[kk], 0.f) * wj;
            }
        }
    }
    // split fp32 -> bf16 hi/lo, store row-major for MFMA A-frag reads (pairs packed as u32)
    #pragma unroll
    for (int kk = 0; kk < 16; kk += 2) {
        int ch = grp * 16 + kk;
        ushort h0 = f2bf(ga[kk]);      ushort l0 = f2bf(ga[kk]     - bf2f(h0));
        ushort h1v = f2bf(ga[kk + 1]); ushort l1v = f2bf(ga[kk + 1] - bf2f(h1v));
        *(uint*)&Hhi[lane * 136 + ch] = (uint)h0 | ((uint)h1v << 16);
        *(uint*)&Hlo[lane * 136 + ch] = (uint)l0 | ((uint)l1v << 16);
    }
    __syncthreads();   // sjd_sh dead from here on

    // ---- MFMA GEMM: 32x128 = Hrow[32][128] @ W2[128][128], wave w owns cols [w*32, w*32+32)
    // mfma_f32_16x16x32_bf16: A row=lane&15, k=(lane>>4)*8+i ; B col=lane&15 ;
    // D col=lane&15, row=(lane>>4)*4+reg  (m89-verified mapping)
    int wv = t >> 6, l = t & 63;
    int l15 = l & 15, lk = l >> 4;
    f32x4 acc00 = {0.f,0.f,0.f,0.f}, acc01 = {0.f,0.f,0.f,0.f};
    f32x4 acc10 = {0.f,0.f,0.f,0.f}, acc11 = {0.f,0.f,0.f,0.f};   // [mt][nt]
    const short8* Bh = (const short8*)w2fh;
    const short8* Bl = (const short8*)w2fl;
    #pragma unroll
    for (int kt = 0; kt < 4; kt++) {
        int ao = l15 * 136 + kt * 32 + lk * 8;
        short8 ah0 = *(const short8*)&Hhi[ao];
        short8 ah1 = *(const short8*)&Hhi[ao + 16 * 136];
        short8 al0 = *(const short8*)&Hlo[ao];
        short8 al1 = *(const short8*)&Hlo[ao + 16 * 136];
        {   // nt = 0
            int ng = 2 * wv;
            short8 bh = Bh[(ng * 4 + kt) * 64 + l];
            short8 bl = Bl[(ng * 4 + kt) * 64 + l];
            acc00 = __builtin_amdgcn_mfma_f32_16x16x32_bf16(ah0, bh, acc00, 0, 0, 0);
            acc00 = __builtin_amdgcn_mfma_f32_16x16x32_bf16(ah0, bl, acc00, 0, 0, 0);
            acc00 = __builtin_amdgcn_mfma_f32_16x16x32_bf16(al0, bh, acc00, 0, 0, 0);
            acc10 = __builtin_amdgcn_mfma_f32_16x16x32_bf16(ah1, bh, acc10, 0, 0, 0);
            acc10 = __builtin_amdgcn_mfma_f32_16x16x32_bf16(ah1, bl, acc10, 0, 0, 0);
            acc10 = __builtin_amdgcn_mfma_f32_16x16x32_bf16(al1, bh, acc10, 0, 0, 0);
        }
        {   // nt = 1
            int ng = 2 * wv + 1;
            short8 bh = Bh[(ng * 4 + kt) * 64 + l];
            short8 bl = Bl[(ng * 4 + kt) * 64 + l];
            acc01 = __builtin_amdgcn_mfma_f32_16x16x32_bf16(ah0, bh, acc01, 0, 0, 0);
            acc01 = __builtin_amdgcn_mfma_f32_16x16x32_bf16(ah0, bl, acc01, 0, 0, 0);
            acc01 = __builtin_amdgcn_mfma_f32_16x16x32_bf16(al0, bh, acc01, 0, 0, 0);
            acc11 = __builtin_amdgcn_mfma_f32_16x16x32_bf16(ah1, bh, acc11, 0, 0, 0);
            acc11 = __builtin_amdgcn_mfma_f32_16x16x32_bf16(ah1, bl, acc11, 0, 0, 0);
            acc11 = __builtin_amdgcn_mfma_f32_16x16x32_bf16(al1, bh, acc11, 0, 0, 0);
        }
    }

    // epilogue: relu(+b2), project to 2 outputs, reduce 16 lanes (cols), cross-wave via LDS
    float p0[2][4], p1[2][4];
    #pragma unroll
    for (int mt = 0; mt < 2; mt++)
        #pragma unroll
        for (int r = 0; r < 4; r++) { p0[mt][r] = 0.f; p1[mt][r] = 0.f; }
    {   // nt = 0
        int colg = (2 * wv) * 16 + l15;
        float b2c = b2[colg], w0 = w3buf[colg * 2], w1c = w3buf[colg * 2 + 1];
        #pragma unroll
        for (int r = 0; r < 4; r++) {
            float v0 = fmaxf(acc00[r] + b2c, 0.f);
            float v1 = fmaxf(acc10[r] + b2c, 0.f);
            p0[0][r] += v0 * w0; p1[0][r] += v0 * w1c;
            p0[1][r] += v1 * w0; p1[1][r] += v1 * w1c;
        }
    }
    {   // nt = 1
        int colg = (2 * wv + 1) * 16 + l15;
        float b2c = b2[colg], w0 = w3buf[colg * 2], w1c = w3buf[colg * 2 + 1];
        #pragma unroll
        for (int r = 0; r < 4; r++) {
            float v0 = fmaxf(acc01[r] + b2c, 0.f);
            float v1 = fmaxf(acc11[r] + b2c, 0.f);
            p0[0][r] += v0 * w0; p1[0][r] += v0 * w1c;
            p0[1][r] += v1 * w0; p1[1][r] += v1 * w1c;
        }
    }
    #pragma unroll
    for (int o = 1; o < 16; o <<= 1) {
        #pragma unroll
        for (int mt = 0; mt < 2; mt++)
            #pragma unroll
            for (int r = 0; r < 4; r++) {
                p0[mt][r] += __shfl_xor(p0[mt][r], o);
                p1[mt][r] += __shfl_xor(p1[mt][r], o);
            }
    }
    float* zpart = (float*)sjd_sh;   // [4 waves][32 rows][2], overlays dead staging buffer
    if (l15 == 0) {
        #pragma unroll
        for (int mt = 0; mt < 2; mt++)
            #pragma unroll
            for (int r = 0; r < 4; r++) {
                int row = mt * 16 + lk * 4 + r;
                zpart[(wv * 32 + row) * 2 + 0] = p0[mt][r];
                zpart[(wv * 32 + row) * 2 + 1] = p1[mt][r];
            }
    }
    __syncthreads();
    if (t < 64) {
        int row = t >> 1, o = t & 1;
        float s = zpart[row * 2 + o] + zpart[(32 + row) * 2 + o]
                + zpart[(64 + row) * 2 + o] + zpart[(96 + row) * 2 + o];
        int rg = r0 + row;
        if (rg < N_NODES) zd[rg * 2 + o] = s * dinv[rg];
    }
}

// ---------------- Layer-3 aggregation + pool: 8 lanes/node, segmented scan, ~2 atomics/block
// into gsum.  NO device fence / ticket (r4-r6 lesson: per-block __threadfence + ticket
// atomic across 1563 blocks cost ~+39 us total).

__global__ void k_aggz(const float* __restrict__ zd, const int* __restrict__ cnt,
                       const int* __restrict__ ell, const float* __restrict__ dinv,
                       const int* __restrict__ batch, float* __restrict__ gsum) {
    __shared__ float sa0[32], sa1[32];
    __shared__ int sg[32];
    int tid = blockIdx.x * 256 + threadIdx.x;
    int t = threadIdx.x;
    int i = tid >> 3, sub = tid & 7;
    const float2* Z = (const float2*)zd;
    float a0 = 0.f, a1 = 0.f;
    if (i < N_NODES) {
        int c = min(cnt[i], MAXDEG);
        for (int p = sub; p < c; p += 8) {
            float2 zj = Z[ell[i * MAXDEG + p]];
            a0 += zj.x; a1 += zj.y;
        }
    }
    a0 += __shfl_xor(a0, 1); a1 += __shfl_xor(a1, 1);
    a0 += __shfl_xor(a0, 2); a1 += __shfl_xor(a1, 2);
    a0 += __shfl_xor(a0, 4); a1 += __shfl_xor(a1, 4);
    if (sub == 0) {
        int li = t >> 3;
        if (i < N_NODES) {
            float di = dinv[i];
            float2 zi = Z[i];
            sa0[li] = (zi.x + a0) * di;     // az_i = zd_i*di + di*Σ zd_j
            sa1[li] = (zi.y + a1) * di;
            sg[li] = batch[i];
        } else { sa0[li] = 0.f; sa1[li] = 0.f; sg[li] = -1; }
    }
    __syncthreads();
    if (t < 32) {
        float v0 = sa0[t], v1 = sa1[t];
        int g = sg[t];
        #pragma unroll
        for (int o = 1; o < 32; o <<= 1) {   // segmented inclusive scan (batch sorted)
            float u0 = __shfl_up(v0, o), u1 = __shfl_up(v1, o);
            int ug = __shfl_up(g, o);
            if (t >= o && ug == g) { v0 += u0; v1 += u1; }
        }
        int gn = __shfl_down(g, 1);
        bool last = (t == 31) || (g != gn);
        if (last && g >= 0) {
            atomicAdd(&gsum[g * 2 + 0], v0);
            atomicAdd(&gsum[g * 2 + 1], v1);
        }
    }
}

// ---------------- Final: 1 block — per-graph mean + consts ----------------

__global__ __launch_bounds__(256) void k_final2(const float* __restrict__ gsum,
                                                const int* __restrict__ starts,
                                                const float* __restrict__ w3buf,
                                                float* __restrict__ out) {
    int t = threadIdx.x;
    for (int g = t; g < NG; g += 256) {
        int c = starts[g + 1] - starts[g];
        if (c > 0) {
            float inv = 1.0f / (float)c;
            out[g * 2 + 0] = gsum[g * 2 + 0] * inv + w3buf[256];
            out[g * 2 + 1] = gsum[g * 2 + 1] * inv + w3buf[257];
        } else {
            out[g * 2 + 0] = w3buf[258];
            out[g * 2 + 1] = w3buf[259];
        }
    }
}

// ---------------- launch ----------------

extern "C" void kernel_launch(void* const* d_in, const int* in_sizes, int n_in,
                              void* d_out, int out_size, void* d_ws, size_t ws_size,
                              hipStream_t stream) {
    const float* x    = (const float*)d_in[0];
    const float* W1   = (const float*)d_in[1];
    const float* b1   = (const float*)d_in[2];
    const float* W2   = (const float*)d_in[3];
    const float* b2   = (const float*)d_in[4];
    const float* W3   = (const float*)d_in[5];
    const float* b3   = (const float*)d_in[6];
    const float* Wlin = (const float*)d_in[7];
    const float* blin = (const float*)d_in[8];
    const int*   eidx = (const int*)d_in[9];
    const int*   batch= (const int*)d_in[10];
    const int* esrc = eidx;
    const int* edst = eidx + N_EDGES;
    float* out = (float*)d_out;

    char* w = (char*)d_ws;
    size_t off = 0;
    auto alloc = [&](size_t bytes) { size_t o = off; off = (off + bytes + 255) & ~(size_t)255; return o; };
    int*   cnt    = (int*)  (w + alloc(N_NODES * 4));
    int*   ell    = (int*)  (w + alloc((size_t)N_NODES * MAXDEG * 4));   // 9.6 MB, node-major
    float* dinv   = (float*)(w + alloc(N_NODES * 4));
    float* xd     = (float*)(w + alloc(N_NODES * 4));
    float2* s1d   = (float2*)(w + alloc((size_t)N_NODES * 8));
    float* w3buf  = (float*)(w + alloc(260 * 4));
    float* zd     = (float*)(w + alloc((size_t)N_NODES * 2 * 4));
    ushort* w2fh  = (ushort*)(w + alloc(16384 * 2));   // W2 bf16-hi, MFMA B-frag order
    ushort* w2fl  = (ushort*)(w + alloc(16384 * 2));   // W2 bf16-lo
    int*   starts = (int*)  (w + alloc((NG + 4) * 4)); // per-graph node range starts
    int*   gcnt   = (int*)  (w + alloc(1024 * 4));     // bucket cursors [782]
    float* gsum   = (float*)(w + alloc(NG * 2 * 4));   // pooled sums (contiguous after gcnt)
    uint*  ebuf   = (uint*) (w + alloc((size_t)NBUCK * BCAP * 4));  // 3.2 MB bucket records

    const int QB = (N_NODES * 8 + 255) / 256;   // 1563 (8 lanes/node)
    // 1: zero bucket cursors + graph accumulators (one contiguous memset)
    hipMemsetAsync(gcnt, 0, 1024 * 4 + NG * 2 * 4, stream);
    // 2: bin edges into bucket chunks + w3lin / starts / W2-frag precompute
    k_bin<<<NEB + 5, 256, 0, stream>>>(esrc, edst, gcnt, ebuf, W2, W3, Wlin, b3, blin,
                                       batch, w3buf, w2fh, w2fl, starts);
    // 3: buckets -> node-major ELL + cnt + dinv + xd (nodeprep fused)
    k_place<<<NBUCK, 256, 0, stream>>>(gcnt, ebuf, x, ell, cnt, dinv, xd);
    // 4: layer-1 scalar aggregate (8 lanes/node, node-major)
    k_s1d<<<QB, 256, 0, stream>>>(xd, dinv, cnt, ell, s1d);
    // 5: fused reconstruct + MFMA GEMM + relu + projection -> zd [N,2]  (r4 32-row monolith)
    k_gemm_fused<<<(N_NODES + 31) / 32, 256, 0, stream>>>(s1d, cnt, ell,
                                                          W1, b1, w2fh, w2fl, b2, w3buf,
                                                          dinv, zd);
    // 6: layer-3 aggregation + pooled segment sums
    k_aggz<<<QB, 256, 0, stream>>>(zd, cnt, ell, dinv, batch, gsum);
    // 7: per-graph mean + consts (1 block)
    k_final2<<<1, 256, 0, stream>>>(gsum, starts, w3buf, out);
}